// Round 15
// baseline (69.713 us; speedup 1.0000x reference)
//
#include <hip/hip_runtime.h>

#define BB    8
#define CC    256
#define HWN   16384       // 128*128
#define PP    30
#define PPAD  32          // padded proto count (2 zero rows)
#define KD    128
#define GG    5
#define XsS   66          // LDS row stride in shorts (33 dwords, odd -> conflict-free)
// d_out float offsets
#define OFF_Q   (33554432u)             // 8*256*128*128
#define OFF_SIM (OFF_Q + 30720u)        // + 30*8*128

typedef float  f32x4 __attribute__((ext_vector_type(4)));
typedef short  short8 __attribute__((ext_vector_type(8)));

static __device__ __forceinline__ unsigned short f2bf(float f) { // f32->bf16 RNE
    unsigned u = __float_as_uint(f);
    u += 0x7fffu + ((u >> 16) & 1u);
    return (unsigned short)(u >> 16);
}

// ---- kernel 1: q-projection + A in bf16 16x16x32-fragment order + c0 -------
// A[b,p,c] = sum_k q[p,b,k]*Wk[k,c]  (rows 30,31 zero)
// A-frag layout for v_mfma_f32_16x16x32_bf16 (half h = p>>4):
//   kb = c>>5, lane = (p&15) + 16*((c>>3)&3), j = c&7
//   Afrag[(((b*2 + h)*8 + kb)*64 + lane)*8 + j]
__global__ __launch_bounds__(256) void proj_kernel(
    const float* __restrict__ proto,  // [P,B,C]
    const float* __restrict__ Wq,     // [6,128,C]
    const float* __restrict__ bq,     // [6,128]
    const float* __restrict__ Wk,     // [128,C]
    const float* __restrict__ bk,     // [128]
    float* __restrict__ qout,         // [P,B,128] (into d_out)
    short* __restrict__ Afrag,        // [B,2,8,64,8] bf16 (ws)
    float* __restrict__ c0)           // [B,PPAD]   (ws)
{
    const int pb = blockIdx.x;        // p*B + b  (p in [0,32))
    const int p = pb / BB, b = pb % BB;
    const int tid = threadIdx.x;      // = channel c

    const int kb = tid >> 5, sub = (tid >> 3) & 3, j = tid & 7;
    const int lane = (p & 15) + 16 * sub;
    const size_t fidx = (((size_t)(b * 2 + (p >> 4)) * 8 + kb) * 64 + lane) * 8 + j;

    if (p >= PP) {                    // pad rows
        Afrag[fidx] = 0;
        if (tid == 0) c0[b * PPAD + p] = -1e30f;
        return;
    }
    const int g = p / GG;

    __shared__ float ps[CC];
    __shared__ float qs[KD];

    for (int c = tid; c < CC; c += 256)
        ps[c] = proto[(size_t)(p * BB + b) * CC + c];
    __syncthreads();

    if (tid < KD) {
        const float* wrow = Wq + (size_t)(g * KD + tid) * CC;
        float a = 0.f;
        #pragma unroll 4
        for (int c = 0; c < CC; ++c) a += ps[c] * wrow[c];
        a += bq[g * KD + tid];
        qout[(size_t)(p * BB + b) * KD + tid] = a;
        qs[tid] = a;
    }
    __syncthreads();

    float a = 0.f;
    #pragma unroll 4
    for (int k = 0; k < KD; ++k) a += qs[k] * Wk[k * CC + tid];
    Afrag[fidx] = (short)f2bf(a);

    if (tid == 0) {
        float s = 0.f;
        for (int k = 0; k < KD; ++k) s += qs[k] * bk[k];
        c0[b * PPAD + p] = s;
    }
}

// ---- kernel 2: 2-tile pipelined bf16-LDS MFMA sim + softmax + out0 ---------
// Block = 256 threads / 4 waves; 2 tiles of 64 positions each. Async-STAGE
// split: tile t+1's 16 global f32x4 loads are issued right after tile t's
// softmax, hiding HBM/L3 latency under tile t's out-store phase.
__global__ __launch_bounds__(256) void fused_kernel(
    const float* __restrict__ X,     // [B,C,HW]
    const short* __restrict__ Afrag, // [B,2,8,64,8] bf16
    const float* __restrict__ c0,    // [B,PPAD]
    float* __restrict__ out0,        // [B,C,HW]
    float* __restrict__ sim)         // [B,PP,HW]
{
    const int b    = blockIdx.y;
    const int tid  = threadIdx.x;
    const int lane = tid & 63;
    const int wid  = tid >> 6;
    const int col  = lane & 15;       // position within wave tile
    const int kgrp = lane >> 4;       // 0..3 (k-subchunk)
    const int t0   = blockIdx.x * 128;

    __shared__ unsigned short Xs[CC * XsS];   // 33792 B
    __shared__ float c0s[PPAD];
    __shared__ float wbuf[64];

    if (tid < PPAD) c0s[tid] = c0[b * PPAD + tid];

    const int ch_s = tid >> 4;        // staging: this thread's base mapping
    const int pq_s = tid & 15;

    // ---- stage tile 0: 16 f32x4 loads -> regs -> LDS (bf16) ----
    f32x4 L[16];
    {
        const float* gb = X + (size_t)b * CC * HWN + t0;
        #pragma unroll
        for (int it = 0; it < 16; ++it)
            L[it] = *(const f32x4*)(gb + (size_t)(it * 16 + ch_s) * HWN + pq_s * 4);
    }
    #pragma unroll
    for (int it = 0; it < 16; ++it) {
        const int ch = it * 16 + ch_s;
        const unsigned lo = (unsigned)f2bf(L[it].x) | ((unsigned)f2bf(L[it].y) << 16);
        const unsigned hi = (unsigned)f2bf(L[it].z) | ((unsigned)f2bf(L[it].w) << 16);
        unsigned* dst = (unsigned*)&Xs[ch * XsS + pq_s * 4];
        dst[0] = lo;
        dst[1] = hi;
    }
    __syncthreads();

    const short8* af8 = (const short8*)Afrag;
    const size_t afbase = (size_t)b * 2 * 8 * 64;

    #pragma unroll
    for (int t = 0; t < 2; ++t) {
        const int n0 = t0 + t * 64;

        // ---- MFMA + softmax ----
        f32x4 accA = {}, accB = {};
        #pragma unroll 2
        for (int kb = 0; kb < 8; ++kb) {
            const short8 afA = af8[afbase + (size_t)kb * 64 + lane];
            const short8 afB = af8[afbase + (size_t)(8 + kb) * 64 + lane];
            short8 bfr;
            #pragma unroll
            for (int j = 0; j < 8; ++j)   // B-frag: k = kgrp*8+j, n = col
                bfr[j] = (short)Xs[(kb * 32 + kgrp * 8 + j) * XsS + wid * 16 + col];
            accA = __builtin_amdgcn_mfma_f32_16x16x32_bf16(afA, bfr, accA, 0, 0, 0);
            accB = __builtin_amdgcn_mfma_f32_16x16x32_bf16(afB, bfr, accB, 0, 0, 0);
        }

        const int nw = n0 + wid * 16;
        float v[8];
        float pm = -1e30f;
        #pragma unroll
        for (int r = 0; r < 4; ++r) {
            const int row = kgrp * 4 + r;
            const float tA = accA[r] + c0s[row];
            const float tB = accB[r] + c0s[row + 16];
            v[r] = tA;
            v[r + 4] = tB;
            pm = fmaxf(pm, fmaxf(tA, tB));
            __builtin_nontemporal_store(tA,
                sim + ((size_t)b * PP + row) * HWN + nw + col);
            if (row + 16 < PP)
                __builtin_nontemporal_store(tB,
                    sim + ((size_t)b * PP + row + 16) * HWN + nw + col);
        }
        float m = pm;
        m = fmaxf(m, __shfl_xor(m, 16));
        m = fmaxf(m, __shfl_xor(m, 32));

        float s = 0.f;
        #pragma unroll
        for (int r = 0; r < 8; ++r)       // pads: exp(-huge) = 0
            s += __expf((v[r] - m) * (1.f / 6.f));
        s += __shfl_xor(s, 16);
        s += __shfl_xor(s, 32);

        if (lane < 16) wbuf[wid * 16 + lane] = 1.f / s;  // max softmax == 1/sum
        __syncthreads();

        // ---- async stage: issue tile-1 loads before the out phase ----
        if (t == 0) {
            const float* gb = X + (size_t)b * CC * HWN + t0 + 64;
            #pragma unroll
            for (int it = 0; it < 16; ++it)
                L[it] = *(const f32x4*)(gb + (size_t)(it * 16 + ch_s) * HWN + pq_s * 4);
        }

        // ---- out0 = unpack(Xs) * w from LDS (nt streams) ----
        {
            const f32x4 w4 = *(const f32x4*)(&wbuf[pq_s * 4]);
            float* ob = out0 + (size_t)b * CC * HWN + n0 + pq_s * 4;
            #pragma unroll 4
            for (int i = 0; i < 16; ++i) {
                const int ch = ch_s * 16 + i;
                const unsigned* src = (const unsigned*)&Xs[ch * XsS + pq_s * 4];
                const unsigned lo = src[0], hi = src[1];
                f32x4 x;
                x.x = __uint_as_float(lo << 16);
                x.y = __uint_as_float(lo & 0xffff0000u);
                x.z = __uint_as_float(hi << 16);
                x.w = __uint_as_float(hi & 0xffff0000u);
                __builtin_nontemporal_store(x * w4, (f32x4*)(ob + (size_t)ch * HWN));
            }
        }

        // ---- commit tile-1 stage to LDS ----
        if (t == 0) {
            __syncthreads();              // everyone done reading Xs(tile0)
            #pragma unroll
            for (int it = 0; it < 16; ++it) {
                const int ch = it * 16 + ch_s;
                const unsigned lo = (unsigned)f2bf(L[it].x) | ((unsigned)f2bf(L[it].y) << 16);
                const unsigned hi = (unsigned)f2bf(L[it].z) | ((unsigned)f2bf(L[it].w) << 16);
                unsigned* dst = (unsigned*)&Xs[ch * XsS + pq_s * 4];
                dst[0] = lo;
                dst[1] = hi;
            }
            __syncthreads();
        }
    }
}

extern "C" void kernel_launch(void* const* d_in, const int* in_sizes, int n_in,
                              void* d_out, int out_size, void* d_ws, size_t ws_size,
                              hipStream_t stream) {
    const float* X     = (const float*)d_in[0];
    const float* proto = (const float*)d_in[1];
    const float* Wk    = (const float*)d_in[2];
    const float* bk    = (const float*)d_in[3];
    const float* Wq    = (const float*)d_in[4];
    const float* bq    = (const float*)d_in[5];

    float* out  = (float*)d_out;
    float* qout = out + OFF_Q;
    float* sim  = out + OFF_SIM;

    short* Afrag = (short*)d_ws;                           // 65536 shorts
    float* c0    = (float*)(Afrag + BB * 2 * 8 * 64 * 8);  // 256 floats

    proj_kernel<<<PPAD * BB, 256, 0, stream>>>(proto, Wq, bq, Wk, bk, qout, Afrag, c0);

    dim3 grid(HWN / 128, BB);                              // 128 x 8 = 1024
    fused_kernel<<<grid, 256, 0, stream>>>(X, Afrag, c0, out, sim);
}

// Round 16
// 67.478 us; speedup vs baseline: 1.0331x; 1.0331x over previous
//
#include <hip/hip_runtime.h>

#define BB    8
#define CC    256
#define HWN   16384       // 128*128
#define PP    30
#define PPAD  32          // padded proto count (2 zero rows)
#define KD    128
#define GG    5
#define XsS   34          // LDS row stride in shorts (17 dwords, odd -> spread)
// d_out float offsets
#define OFF_Q   (33554432u)             // 8*256*128*128
#define OFF_SIM (OFF_Q + 30720u)        // + 30*8*128

typedef float  f32x4 __attribute__((ext_vector_type(4)));
typedef short  short8 __attribute__((ext_vector_type(8)));

static __device__ __forceinline__ unsigned short f2bf(float f) { // f32->bf16 RNE
    unsigned u = __float_as_uint(f);
    u += 0x7fffu + ((u >> 16) & 1u);
    return (unsigned short)(u >> 16);
}

// ---- kernel 1: q-projection + A in bf16 16x16x32-fragment order + c0 -------
// A[b,p,c] = sum_k q[p,b,k]*Wk[k,c]  (rows 30,31 zero)
// A-frag layout for v_mfma_f32_16x16x32_bf16 (half h = p>>4):
//   kb = c>>5, lane = (p&15) + 16*((c>>3)&3), j = c&7
//   Afrag[(((b*2 + h)*8 + kb)*64 + lane)*8 + j]
__global__ __launch_bounds__(256) void proj_kernel(
    const float* __restrict__ proto,  // [P,B,C]
    const float* __restrict__ Wq,     // [6,128,C]
    const float* __restrict__ bq,     // [6,128]
    const float* __restrict__ Wk,     // [128,C]
    const float* __restrict__ bk,     // [128]
    float* __restrict__ qout,         // [P,B,128] (into d_out)
    short* __restrict__ Afrag,        // [B,2,8,64,8] bf16 (ws)
    float* __restrict__ c0)           // [B,PPAD]   (ws)
{
    const int pb = blockIdx.x;        // p*B + b  (p in [0,32))
    const int p = pb / BB, b = pb % BB;
    const int tid = threadIdx.x;      // = channel c

    const int kb = tid >> 5, sub = (tid >> 3) & 3, j = tid & 7;
    const int lane = (p & 15) + 16 * sub;
    const size_t fidx = (((size_t)(b * 2 + (p >> 4)) * 8 + kb) * 64 + lane) * 8 + j;

    if (p >= PP) {                    // pad rows
        Afrag[fidx] = 0;
        if (tid == 0) c0[b * PPAD + p] = -1e30f;
        return;
    }
    const int g = p / GG;

    __shared__ float ps[CC];
    __shared__ float qs[KD];

    for (int c = tid; c < CC; c += 256)
        ps[c] = proto[(size_t)(p * BB + b) * CC + c];
    __syncthreads();

    if (tid < KD) {
        const float* wrow = Wq + (size_t)(g * KD + tid) * CC;
        float a = 0.f;
        #pragma unroll 4
        for (int c = 0; c < CC; ++c) a += ps[c] * wrow[c];
        a += bq[g * KD + tid];
        qout[(size_t)(p * BB + b) * KD + tid] = a;
        qs[tid] = a;
    }
    __syncthreads();

    float a = 0.f;
    #pragma unroll 4
    for (int k = 0; k < KD; ++k) a += qs[k] * Wk[k * CC + tid];
    Afrag[fidx] = (short)f2bf(a);

    if (tid == 0) {
        float s = 0.f;
        for (int k = 0; k < KD; ++k) s += qs[k] * bk[k];
        c0[b * PPAD + p] = s;
    }
}

// ---- kernel 2: 2-wave / 32-pos bf16-LDS MFMA sim + softmax + out0 ----------
// Block = 128 threads / 2 waves / 32 positions; 17.5 KB LDS -> 9 blocks/CU
// (18 waves/CU of independent phase-diverse pipelines; barriers couple only
// 2 waves). Wave w: 16 pos via 8 K-steps x 2 mfma_f32_16x16x32_bf16 with
// af-fragments preloaded to registers; softmax via shfl_xor; out0 from LDS.
__global__ __launch_bounds__(128, 4) void fused_kernel(
    const float* __restrict__ X,     // [B,C,HW]
    const short* __restrict__ Afrag, // [B,2,8,64,8] bf16
    const float* __restrict__ c0,    // [B,PPAD]
    float* __restrict__ out0,        // [B,C,HW]
    float* __restrict__ sim)         // [B,PP,HW]
{
    const int b    = blockIdx.y;
    const int tid  = threadIdx.x;
    const int lane = tid & 63;
    const int w    = tid >> 6;        // wave id (0,1)
    const int col  = lane & 15;       // position within wave tile
    const int kgrp = lane >> 4;       // 0..3 (k-subchunk)
    const int n0   = blockIdx.x * 32;
    const int nw   = n0 + w * 16;

    __shared__ unsigned short Xs[CC * XsS];   // 17408 B
    __shared__ float c0s[PPAD];
    __shared__ float wbuf[32];

    if (tid < PPAD) c0s[tid] = c0[b * PPAD + tid];

    // ---- preload A-fragments (16 x 16B, L2-hot, latency hidden by staging) --
    const short8* af8 = (const short8*)Afrag;
    const size_t afbase = (size_t)b * 2 * 8 * 64;
    short8 afA[8], afB[8];
    #pragma unroll
    for (int kb = 0; kb < 8; ++kb) {
        afA[kb] = af8[afbase + (size_t)kb * 64 + lane];
        afB[kb] = af8[afbase + (size_t)(8 + kb) * 64 + lane];
    }

    // ---- phase 1: stage X tile as bf16 (16 f32x4/thread, batched 4) --------
    const int ch_s = tid >> 3;        // 0..15
    const int pq_s = tid & 7;         // 0..7 (4 positions each)
    {
        const float* gb = X + (size_t)b * CC * HWN + n0;
        #pragma unroll
        for (int it = 0; it < 4; ++it) {
            f32x4 v[4];
            #pragma unroll
            for (int u = 0; u < 4; ++u) {
                const int ch = (it * 4 + u) * 16 + ch_s;
                v[u] = *(const f32x4*)(gb + (size_t)ch * HWN + pq_s * 4);
            }
            #pragma unroll
            for (int u = 0; u < 4; ++u) {
                const int ch = (it * 4 + u) * 16 + ch_s;
                const unsigned lo = (unsigned)f2bf(v[u].x) | ((unsigned)f2bf(v[u].y) << 16);
                const unsigned hi = (unsigned)f2bf(v[u].z) | ((unsigned)f2bf(v[u].w) << 16);
                unsigned* dst = (unsigned*)&Xs[ch * XsS + pq_s * 4];
                dst[0] = lo;
                dst[1] = hi;
            }
        }
    }
    __syncthreads();

    // ---- phase 2: MFMA + softmax (per-wave) ---------------------------------
    f32x4 accA = {}, accB = {};
    #pragma unroll
    for (int kb = 0; kb < 8; ++kb) {
        short8 bfr;
        #pragma unroll
        for (int j = 0; j < 8; ++j)   // B-frag: k = kgrp*8+j, n = col
            bfr[j] = (short)Xs[(kb * 32 + kgrp * 8 + j) * XsS + w * 16 + col];
        accA = __builtin_amdgcn_mfma_f32_16x16x32_bf16(afA[kb], bfr, accA, 0, 0, 0);
        accB = __builtin_amdgcn_mfma_f32_16x16x32_bf16(afB[kb], bfr, accB, 0, 0, 0);
    }

    // C/D: col = lane&15, row = (lane>>4)*4 + r; accA rows=protos, accB +16
    float v[8];
    float pm = -1e30f;
    #pragma unroll
    for (int r = 0; r < 4; ++r) {
        const int row = kgrp * 4 + r;
        const float tA = accA[r] + c0s[row];
        const float tB = accB[r] + c0s[row + 16];
        v[r] = tA;
        v[r + 4] = tB;
        pm = fmaxf(pm, fmaxf(tA, tB));
        __builtin_nontemporal_store(tA,
            sim + ((size_t)b * PP + row) * HWN + nw + col);
        if (row + 16 < PP)
            __builtin_nontemporal_store(tB,
                sim + ((size_t)b * PP + row + 16) * HWN + nw + col);
    }
    float m = pm;
    m = fmaxf(m, __shfl_xor(m, 16));
    m = fmaxf(m, __shfl_xor(m, 32));

    float s = 0.f;
    #pragma unroll
    for (int r = 0; r < 8; ++r)       // pads: exp(-huge) = 0
        s += __expf((v[r] - m) * (1.f / 6.f));
    s += __shfl_xor(s, 16);
    s += __shfl_xor(s, 32);

    if (lane < 16) wbuf[w * 16 + lane] = 1.f / s;   // max softmax == 1/sum exp
    __syncthreads();

    // ---- phase 3: out0 = unpack(Xs) * w from LDS (nt f32x4 streams) ---------
    const f32x4 w4 = *(const f32x4*)(&wbuf[pq_s * 4]);
    float* ob = out0 + (size_t)b * CC * HWN + n0 + pq_s * 4;
    #pragma unroll 4
    for (int i = 0; i < 16; ++i) {
        const int ch = ch_s * 16 + i;
        const unsigned* src = (const unsigned*)&Xs[ch * XsS + pq_s * 4];
        const unsigned lo = src[0], hi = src[1];
        f32x4 x;
        x.x = __uint_as_float(lo << 16);
        x.y = __uint_as_float(lo & 0xffff0000u);
        x.z = __uint_as_float(hi << 16);
        x.w = __uint_as_float(hi & 0xffff0000u);
        __builtin_nontemporal_store(x * w4, (f32x4*)(ob + (size_t)ch * HWN));
    }
}

extern "C" void kernel_launch(void* const* d_in, const int* in_sizes, int n_in,
                              void* d_out, int out_size, void* d_ws, size_t ws_size,
                              hipStream_t stream) {
    const float* X     = (const float*)d_in[0];
    const float* proto = (const float*)d_in[1];
    const float* Wk    = (const float*)d_in[2];
    const float* bk    = (const float*)d_in[3];
    const float* Wq    = (const float*)d_in[4];
    const float* bq    = (const float*)d_in[5];

    float* out  = (float*)d_out;
    float* qout = out + OFF_Q;
    float* sim  = out + OFF_SIM;

    short* Afrag = (short*)d_ws;                           // 65536 shorts
    float* c0    = (float*)(Afrag + BB * 2 * 8 * 64 * 8);  // 256 floats

    proj_kernel<<<PPAD * BB, 256, 0, stream>>>(proto, Wq, bq, Wk, bk, qout, Afrag, c0);

    dim3 grid(HWN / 32, BB);                               // 512 x 8 = 4096
    fused_kernel<<<grid, 128, 0, stream>>>(X, Afrag, c0, out, sim);
}